// Round 10
// baseline (4595.851 us; speedup 1.0000x reference)
//
#include <hip/hip_runtime.h>
#include <hip/hip_bf16.h>
#include <cstdint>

// ---------------------------------------------------------------------------
// 2-layer LSTM (B=512, T=128, F=64, H=1024) + dense sigmoid head.
// R10: persistent kernel (all 128 steps, one launch) with a CUSTOM grid
// barrier: device-scope atomics + explicit agent release/acquire fences
// (buffer_wbl2/buffer_inv on gfx950) -- the cross-XCD cache maintenance that
// dispatch boundaries provided and cg::grid.sync() did not (R9 failed with
// stale h reads: absmax 0.127). Normal launch, grid 256 = 1 block/CU
// (<= capacity -> co-resident). Per-step compute = R8 zero-LDS granule
// K-loop: fragments in MFMA-granule layout (1 KB = 16 rows x 32 k),
// register ping-pong with DISTINCT FragSet variables (R5 spill lesson).
// ---------------------------------------------------------------------------

typedef __attribute__((ext_vector_type(8))) _Float16 half8;
typedef __attribute__((ext_vector_type(4))) float    float4v;

__device__ __forceinline__ float sigf(float x) { return 1.0f / (1.0f + __expf(-x)); }
__device__ __forceinline__ float tanhfast(float x) { return 2.0f * sigf(2.0f * x) - 1.0f; }

static constexpr size_t HPS = 32ull * 32 * 512;   // packed h slot (elems)

struct FragSet {          // one BK=128 stage for one wave (128 VGPR)
    half8 A[4][4];        // [msub][kcl]
    half8 B[4][4];        // [kcl][gate]
};

// Sense-reversing grid barrier with explicit cross-XCD cache maintenance.
// Release fence: buffer_wbl2 sc1 (dirty L2 -> LLC). Acquire fence:
// buffer_inv sc1 (invalidate stale L2/L1). Spin uses RELAXED device-scope
// atomic loads (sc-bypassed to the coherent point); one acquire fence after.
__device__ __forceinline__ void grid_barrier(int* cnt, int* gen, int nb)
{
    __syncthreads();                      // all block stores issued (vmcnt(0))
    if (threadIdx.x == 0) {
        __builtin_amdgcn_fence(__ATOMIC_RELEASE, "agent");
        const int g = __hip_atomic_load(gen, __ATOMIC_RELAXED, __HIP_MEMORY_SCOPE_AGENT);
        const int a = __hip_atomic_fetch_add(cnt, 1, __ATOMIC_ACQ_REL, __HIP_MEMORY_SCOPE_AGENT);
        if (a == nb - 1) {
            __hip_atomic_store(cnt, 0, __ATOMIC_RELAXED, __HIP_MEMORY_SCOPE_AGENT);
            __hip_atomic_fetch_add(gen, 1, __ATOMIC_RELEASE, __HIP_MEMORY_SCOPE_AGENT);
        } else {
            while (__hip_atomic_load(gen, __ATOMIC_RELAXED, __HIP_MEMORY_SCOPE_AGENT) == g)
                __builtin_amdgcn_s_sleep(1);
        }
        __builtin_amdgcn_fence(__ATOMIC_ACQUIRE, "agent");
    }
    __syncthreads();
}

// ---------------------------------------------------------------------------
// Persistent pipeline: step s (0..128): role-0 blocks run layer1 t=s
// (skip s==128), role-1 blocks run layer2 t=s-1 (skip s==0); barrier between
// steps (none after the last -- kernel end is a dispatch boundary).
// b: role=(b>>3)&1, tile=((b>>4)<<3)|(b&7); XCD (b%8) = n-strip low bits for
// both roles. Block tile 128m x 32n x 4 gates; wave tile 64m x 16n x 4.
// Slot parity: layer1(t) writes h1[1-(t&1)]; layer2(t) reads h1[1-(t&1)],
// h2[t&1], writes h2[1-(t&1)] -- race-free with one barrier per step.
// ---------------------------------------------------------------------------
__global__ __launch_bounds__(256, 1) void fused_all(
    const _Float16* __restrict__ xp,   // packed x: ((t*32+mG)*2+kc)*512
    const _Float16* __restrict__ P1,   // packed layer1 weights, KCB=34
    const _Float16* __restrict__ P2,   // packed layer2 weights, KCB=64
    const float* __restrict__ b1, float* __restrict__ c1, _Float16* __restrict__ h1p,
    const float* __restrict__ b2, float* __restrict__ c2, _Float16* __restrict__ h2p,
    int* __restrict__ bar)
{
    int* cnt = bar;
    int* gen = bar + 64;                   // separate cache lines

    const int b    = blockIdx.x;
    const int role = (b >> 3) & 1;
    const int tile = ((b >> 4) << 3) | (b & 7);    // 0..127

    const int tid = threadIdx.x;
    const int w   = tid >> 6;
    const int l   = tid & 63;
    const int q   = l >> 4;
    const int c16 = l & 15;
    const int mh  = w & 1;             // 64-row half
    const int nh  = w >> 1;            // 16-unit half

    const int m0  = (tile >> 5) * 128;
    const int n0  = (tile & 31) * 32;
    const int mG0 = (m0 >> 4) + mh * 4;    // wave's first A granule (of 4)
    const size_t l8 = (size_t)l * 8;

    // ---- loop-invariant per-role setup ----
    const _Float16* Pk = role ? P2 : P1;
    const int KCB = role ? 64 : 34;        // B granule stride = total kc
    const int KC0 = role ? 32 : 2;         // A segment-0 granule stride/len
    const float* bias = role ? b2 : b1;
    float* cs = role ? c2 : c1;

    const _Float16* bp[4];                 // per-gate packed-B granule base
#pragma unroll
    for (int g = 0; g < 4; ++g)
        bp[g] = Pk + ((size_t)(g * 64 + (n0 >> 4) + nh) * KCB) * 512 + l8;

    const int ng = n0 + nh * 16 + c16;
    const float bi  = bias[ng];
    const float bff = bias[1024 + ng];
    const float bg  = bias[2048 + ng];
    const float bo  = bias[3072 + ng];
    const int kcH   = n0 >> 5;
    const int laneW = (nh * 2 + (c16 >> 3)) << 4;
    const int jW    = c16 & 7;
    const int NS    = KCB >> 2;            // BK128 stages: 8 (l1) / 16 (l2)

    for (int s = 0; s <= 128; ++s) {
        const int t = role ? s - 1 : s;
        if (t >= 0 && t < 128) {
            const int par = t & 1;
            const _Float16 *As0, *As1; _Float16* hop;
            if (role == 0) {
                As0 = xp + (size_t)t * 32768;          // x(t), stride 2/mG
                As1 = h1p + (size_t)par * HPS;         // h1(t-1)
                hop = h1p + (size_t)(1 - par) * HPS;
            } else {
                As0 = h1p + (size_t)(1 - par) * HPS;   // h1(t)
                As1 = h2p + (size_t)par * HPS;         // h2(t-1)
                hop = h2p + (size_t)(1 - par) * HPS;
            }

            float4v acc[4][4] = {};        // [gate][msub]

            auto loadS = [&](int st, FragSet& S) {
#pragma unroll
                for (int kcl = 0; kcl < 4; ++kcl) {
                    const int kc = st * 4 + kcl;
                    const _Float16* ab; size_t astr;
                    if (kc < KC0) { ab = As0 + (size_t)kc * 512;         astr = (size_t)KC0 * 512; }
                    else          { ab = As1 + (size_t)(kc - KC0) * 512; astr = 32ull * 512; }
                    ab += (size_t)mG0 * astr + l8;
#pragma unroll
                    for (int ms = 0; ms < 4; ++ms)
                        S.A[ms][kcl] = *(const half8*)(ab + (size_t)ms * astr);
#pragma unroll
                    for (int g = 0; g < 4; ++g)
                        S.B[kcl][g] = *(const half8*)(bp[g] + (size_t)kc * 512);
                }
            };
            auto computeS = [&](const FragSet& S) {
#pragma unroll
                for (int kcl = 0; kcl < 4; ++kcl)
#pragma unroll
                    for (int g = 0; g < 4; ++g)
#pragma unroll
                        for (int ms = 0; ms < 4; ++ms)
                            acc[g][ms] = __builtin_amdgcn_mfma_f32_16x16x32_f16(
                                S.A[ms][kcl], S.B[kcl][g], acc[g][ms], 0, 0, 0);
            };

            FragSet S0, S1;                // DISTINCT variables (no dyn indexing)
            loadS(0, S0);
            for (int st = 0; st + 2 <= NS; st += 2) {
                loadS(st + 1, S1);
                computeS(S0);
                if (st + 2 < NS) loadS(st + 2, S0);
                computeS(S1);
            }
            if (KCB & 3) {                 // layer1 tail: kc 32,33 (from As1)
                half8 At[4][2], Bt[2][4];
#pragma unroll
                for (int kcl = 0; kcl < 2; ++kcl) {
                    const int kc = NS * 4 + kcl;
                    const _Float16* ab = As1 + (size_t)(kc - KC0) * 512
                                       + (size_t)mG0 * (32ull * 512) + l8;
#pragma unroll
                    for (int ms = 0; ms < 4; ++ms)
                        At[ms][kcl] = *(const half8*)(ab + (size_t)ms * (32ull * 512));
#pragma unroll
                    for (int g = 0; g < 4; ++g)
                        Bt[kcl][g] = *(const half8*)(bp[g] + (size_t)kc * 512);
                }
#pragma unroll
                for (int kcl = 0; kcl < 2; ++kcl)
#pragma unroll
                    for (int g = 0; g < 4; ++g)
#pragma unroll
                        for (int ms = 0; ms < 4; ++ms)
                            acc[g][ms] = __builtin_amdgcn_mfma_f32_16x16x32_f16(
                                At[ms][kcl], Bt[kcl][g], acc[g][ms], 0, 0, 0);
            }

            // ---- fused gate epilogue; h written in A-granule layout ----
#pragma unroll
            for (int ms = 0; ms < 4; ++ms) {
                const int mG = mG0 + ms;
                _Float16* hg = hop + ((size_t)(mG * 32 + kcH)) * 512
                             + (size_t)laneW * 8 + jW;
#pragma unroll
                for (int i = 0; i < 4; ++i) {
                    const int m = m0 + mh * 64 + ms * 16 + q * 4 + i;
                    const float zi = acc[0][ms][i] + bi;
                    const float zf = acc[1][ms][i] + bff;
                    const float zg = acc[2][ms][i] + bg;
                    const float zo = acc[3][ms][i] + bo;
                    const float ig = sigf(zi);
                    const float fg = sigf(zf);
                    const float gg = tanhfast(zg);
                    const float og = sigf(zo);
                    const size_t cidx = (size_t)m * 1024 + ng;
                    const float cc = fg * cs[cidx] + ig * gg;
                    cs[cidx] = cc;
                    hg[(q * 4 + i) * 8] = (_Float16)(og * tanhfast(cc));
                }
            }
        }
        if (s < 128) grid_barrier(cnt, gen, 256);
    }
}

// ---------------------------------------------------------------------------
// Pack [W (KA,4096) | U (K-KA,4096)] fp32 row-major into B-fragment granules.
// ---------------------------------------------------------------------------
__global__ void pack_weights(const float* __restrict__ W, const float* __restrict__ U,
                             int KA, int KC, _Float16* __restrict__ out)
{
    const size_t e = (size_t)blockIdx.x * blockDim.x + threadIdx.x;
    const size_t total = (size_t)256 * KC * 512;
    if (e >= total) return;
    const int j    = (int)(e & 7);
    const int lane = (int)((e >> 3) & 63);
    const size_t g = e >> 9;
    const int kc  = (int)(g % KC);
    const int ntG = (int)(g / KC);
    const int col = ntG * 16 + (lane & 15);
    const int k   = kc * 32 + (lane >> 4) * 8 + j;
    const float v = (k < KA) ? W[(size_t)k * 4096 + col]
                             : U[(size_t)(k - KA) * 4096 + col];
    out[e] = (_Float16)v;
}

// ---------------------------------------------------------------------------
// Pack x (B=512, T=128, F=64) fp32 into per-timestep A-granules.
// ---------------------------------------------------------------------------
__global__ void pack_x(const float* __restrict__ x, _Float16* __restrict__ xp)
{
    const int e = blockIdx.x * blockDim.x + threadIdx.x;
    if (e >= 512 * 128 * 64) return;
    const int j  = e & 7;
    const int l  = (e >> 3) & 63;
    const int g  = e >> 9;
    const int kc = g & 1;
    const int tm = g >> 1;
    const int mG = tm & 31;
    const int t  = tm >> 5;
    const int m  = mG * 16 + (l & 15);
    const int f  = kc * 32 + (l >> 4) * 8 + j;
    xp[e] = (_Float16)x[((size_t)m * 128 + t) * 64 + f];
}

// ---------------------------------------------------------------------------
// Dense head on packed h2: out[m] = sigmoid(h2[m,:].Wd + bd).
// ---------------------------------------------------------------------------
__global__ __launch_bounds__(64) void dense_head(const _Float16* __restrict__ h2p,
                                                 const float* __restrict__ Wd,
                                                 const float* __restrict__ bd,
                                                 float* __restrict__ out)
{
    const int mG = blockIdx.x;
    const int l  = threadIdx.x;
    float s = 0.0f;
    for (int kc = 0; kc < 32; ++kc) {
        half8 f = *(const half8*)(h2p + ((size_t)(mG * 32 + kc)) * 512 + (size_t)l * 8);
        const int kb = kc * 32 + (l >> 4) * 8;
#pragma unroll
        for (int j = 0; j < 8; ++j) s += (float)f[j] * Wd[kb + j];
    }
    s += __shfl_xor(s, 16);
    s += __shfl_xor(s, 32);
    if (l < 16) out[mG * 16 + l] = 1.0f / (1.0f + __expf(-(s + bd[0])));
}

// ---------------------------------------------------------------------------

extern "C" void kernel_launch(void* const* d_in, const int* in_sizes, int n_in,
                              void* d_out, int out_size, void* d_ws, size_t ws_size,
                              hipStream_t stream)
{
    const float* x  = (const float*)d_in[0];
    const float* W1 = (const float*)d_in[1];
    const float* U1 = (const float*)d_in[2];
    const float* b1 = (const float*)d_in[3];
    const float* W2 = (const float*)d_in[4];
    const float* U2 = (const float*)d_in[5];
    const float* b2 = (const float*)d_in[6];
    const float* Wd = (const float*)d_in[7];
    const float* bd = (const float*)d_in[8];
    float* out = (float*)d_out;

    char* ws = (char*)d_ws;
    size_t off = 0;
    auto alloc = [&](size_t bytes) {
        char* p = ws + off;
        off = (off + bytes + 255) & ~(size_t)255;
        return p;
    };
    _Float16* xp  = (_Float16*)alloc(512ull * 128 * 64 * 2);  // packed x
    _Float16* P1  = (_Float16*)alloc(256ull * 34 * 512 * 2);  // packed layer1 W|U
    _Float16* P2  = (_Float16*)alloc(256ull * 64 * 512 * 2);  // packed layer2 W|U
    _Float16* h1p = (_Float16*)alloc(2ull * HPS * 2);         // packed h1 ping-pong
    _Float16* h2p = (_Float16*)alloc(2ull * HPS * 2);         // packed h2 ping-pong
    float*    c1  = (float*)alloc(512ull * 1024 * 4);
    float*    c2  = (float*)alloc(512ull * 1024 * 4);
    int*      bar = (int*)alloc(512);                         // barrier cnt/gen

    // zero initial state (ws is re-poisoned to 0xAA before every launch)
    hipMemsetAsync(c1, 0, 512ull * 1024 * 4, stream);
    hipMemsetAsync(c2, 0, 512ull * 1024 * 4, stream);
    hipMemsetAsync(h1p, 0, HPS * 2, stream);   // slot 0 (read at t=0)
    hipMemsetAsync(h2p, 0, HPS * 2, stream);   // slot 0
    hipMemsetAsync(bar, 0, 512, stream);

    pack_x<<<(512 * 128 * 64 + 255) / 256, 256, 0, stream>>>(x, xp);
    pack_weights<<<(256 * 34 * 512 + 255) / 256, 256, 0, stream>>>(W1, U1, 64, 34, P1);
    pack_weights<<<(256 * 64 * 512 + 255) / 256, 256, 0, stream>>>(W2, U2, 1024, 64, P2);

    // one persistent launch: 256 blocks = 1/CU (co-resident), 128 barriers
    fused_all<<<256, 256, 0, stream>>>(xp, P1, P2,
                                       b1, c1, h1p, b2, c2, h2p, bar);

    // h2(127) lands in slot 0
    dense_head<<<32, 64, 0, stream>>>(h2p, Wd, bd, out);
}